// Round 12
// baseline (511.872 us; speedup 1.0000x reference)
//
#include <hip/hip_runtime.h>
#include <hip/hip_fp16.h>

#define NN   50000
#define EE   800000
#define ETOT 850000   // EE + NN self loops
#define FIN  128
#define HC   256      // H*C
#define NH   4
#define CH   64
#define NG   64
#define NOUT 16
#define NEG_SLOPE 0.2f

#define NBUCK 391     // ceil(NN/128) dst-range buckets
#define BCAP  4096    // slots per bucket
#define EPB   4096    // edges per phase-1 block
#define NEB   208     // ceil(ETOT/EPB)

typedef _Float16 f16x8 __attribute__((ext_vector_type(8)));
typedef float    f32x4 __attribute__((ext_vector_type(4)));

// ======== CSR build: 2-phase dst-range bucketing ========
__global__ __launch_bounds__(256) void edge_bucket(const int* __restrict__ ei,
                                                   int* __restrict__ bucket_counts,
                                                   unsigned* __restrict__ buckets) {
    __shared__ int h[NBUCK];
    __shared__ int bb[NBUCK];
    const int tid = threadIdx.x;
    const int e0  = blockIdx.x * EPB;

    for (int t = tid; t < NBUCK; t += 256) h[t] = 0;
    __syncthreads();

    int srcs[16], dsts[16];
#pragma unroll
    for (int k = 0; k < 16; ++k) {
        int i = e0 + k * 256 + tid;
        int s = 0, d = -1;
        if (i < ETOT) {
            s = (i < EE) ? ei[i] : (i - EE);
            d = (i < EE) ? ei[EE + i] : (i - EE);
            atomicAdd(&h[d >> 7], 1);
        }
        srcs[k] = s; dsts[k] = d;
    }
    __syncthreads();

    for (int t = tid; t < NBUCK; t += 256) {
        bb[t] = atomicAdd(&bucket_counts[t], h[t]);
        h[t]  = 0;
    }
    __syncthreads();

#pragma unroll
    for (int k = 0; k < 16; ++k) {
        int d = dsts[k];
        if (d >= 0) {
            int b = d >> 7;
            int r = atomicAdd(&h[b], 1);
            int idx = bb[b] + r;
            if (idx < BCAP)
                buckets[(size_t)b * BCAP + idx] =
                    (unsigned)srcs[k] | ((unsigned)(d & 127) << 16);
        }
    }
}

__global__ __launch_bounds__(512) void bucket_scan(const int* __restrict__ counts,
                                                   int* __restrict__ basep,
                                                   int* __restrict__ rowptr) {
    __shared__ int lds[512];
    const int tid = threadIdx.x;
    int v = (tid < NBUCK) ? counts[tid] : 0;
    lds[tid] = v;
    __syncthreads();
    for (int off = 1; off < 512; off <<= 1) {
        int t = (tid >= off) ? lds[tid - off] : 0;
        __syncthreads();
        lds[tid] += t;
        __syncthreads();
    }
    if (tid < NBUCK) basep[tid] = lds[tid] - v;
    if (tid == 0) rowptr[NN] = ETOT;
}

__global__ __launch_bounds__(256) void bucket_to_csr(const unsigned* __restrict__ buckets,
                                                     const int* __restrict__ bucket_counts,
                                                     const int* __restrict__ bucket_base,
                                                     int* __restrict__ rowptr,
                                                     int* __restrict__ csr) {
    __shared__ int h[128], c[128], sc[128];
    const int b = blockIdx.x, tid = threadIdx.x;
    const int nb   = bucket_counts[b];
    const int base = bucket_base[b];

    if (tid < 128) h[tid] = 0;
    __syncthreads();
    for (int i = tid; i < nb; i += 256) {
        unsigned p = buckets[(size_t)b * BCAP + i];
        atomicAdd(&h[p >> 16], 1);
    }
    __syncthreads();
    if (tid < 128) sc[tid] = h[tid];
    __syncthreads();
    for (int off = 1; off < 128; off <<= 1) {
        int t = (tid < 128 && tid >= off) ? sc[tid - off] : 0;
        __syncthreads();
        if (tid < 128) sc[tid] += t;
        __syncthreads();
    }
    if (tid < 128) {
        int excl = sc[tid] - h[tid];
        c[tid] = excl;
        int node = (b << 7) + tid;
        if (node < NN) rowptr[node] = base + excl;
    }
    __syncthreads();
    for (int i = tid; i < nb; i += 256) {
        unsigned p = buckets[(size_t)b * BCAP + i];
        int pos = atomicAdd(&c[p >> 16], 1);
        csr[base + pos] = (int)(p & 0xFFFFu);
    }
}

// ---------------- dtype conversions ----------------
__global__ void f32_to_f16_vec(const float* __restrict__ in, __half* __restrict__ out,
                               int n4) {
    int i = blockIdx.x * 256 + threadIdx.x;
    if (i >= n4) return;
    float4 v = *(const float4*)&in[(size_t)i * 4];
    __half h[4] = {__float2half(v.x), __float2half(v.y), __float2half(v.z), __float2half(v.w)};
    *(uint2*)&out[(size_t)i * 4] = *(uint2*)h;
}

__global__ void w_transpose_f16(const float* __restrict__ W, __half* __restrict__ Wt,
                                int K) {
    int idx = blockIdx.x * 256 + threadIdx.x;
    if (idx >= K * HC) return;
    int n = idx / K, k = idx - n * K;
    Wt[idx] = __float2half(W[(size_t)k * HC + n]);
}

// ---- f16 MFMA GEMM + fused attention-score epilogue ----
__global__ __launch_bounds__(256) void gemm_f16(const __half* __restrict__ A16,
                                                const __half* __restrict__ Bt16,
                                                __half* __restrict__ C16,
                                                const float* __restrict__ a_src,
                                                const float* __restrict__ a_dst,
                                                float* __restrict__ es,
                                                float* __restrict__ ed,
                                                int M, int K) {
    __shared__ char lds[32768];
    const int tid  = threadIdx.x;
    const int m0   = blockIdx.y * 128;
    const int n0   = blockIdx.x * 128;
    const int wid  = tid >> 6, lane = tid & 63;
    const int wr   = wid >> 1, wc = wid & 1;
    const int l15  = lane & 15, l4 = lane >> 4;
    const int trow = tid >> 3;
    const int tcol = (tid & 7) * 8;

    f32x4 acc[4][4] = {};

    for (int k0 = 0; k0 < K; k0 += 64) {
        __syncthreads();
#pragma unroll
        for (int it = 0; it < 4; ++it) {
            int row = trow + it * 32;
            uint4 v = make_uint4(0u, 0u, 0u, 0u);
            int gr = m0 + row;
            if (gr < M) v = *(const uint4*)&A16[(size_t)gr * K + k0 + tcol];
            int off = (row * 128 + tcol * 2) ^ ((row & 7) << 4);
            *(uint4*)(lds + off) = v;
            uint4 w = *(const uint4*)&Bt16[(size_t)(n0 + row) * K + k0 + tcol];
            int offb = 16384 + ((row * 128 + tcol * 2) ^ ((row & 7) << 4));
            *(uint4*)(lds + offb) = w;
        }
        __syncthreads();
#pragma unroll
        for (int ks = 0; ks < 2; ++ks) {
            f16x8 af[4], bf[4];
#pragma unroll
            for (int i = 0; i < 4; ++i) {
                int rowA = wr * 64 + i * 16 + l15;
                int offA = (rowA * 128 + ks * 64 + l4 * 16) ^ ((rowA & 7) << 4);
                af[i] = *(const f16x8*)(lds + offA);
                int rowB = wc * 64 + i * 16 + l15;
                int offB = 16384 + ((rowB * 128 + ks * 64 + l4 * 16) ^ ((rowB & 7) << 4));
                bf[i] = *(const f16x8*)(lds + offB);
            }
#pragma unroll
            for (int i = 0; i < 4; ++i)
#pragma unroll
                for (int j = 0; j < 4; ++j)
                    acc[i][j] = __builtin_amdgcn_mfma_f32_16x16x32_f16(af[i], bf[j], acc[i][j], 0, 0, 0);
        }
    }
#pragma unroll
    for (int i = 0; i < 4; ++i) {
#pragma unroll
        for (int r = 0; r < 4; ++r) {
            int row = m0 + wr * 64 + i * 16 + l4 * 4 + r;
            if (row < M) {
#pragma unroll
                for (int j = 0; j < 4; ++j) {
                    int col = n0 + wc * 64 + j * 16 + l15;
                    C16[(size_t)row * HC + col] = __float2half(acc[i][j][r]);
                }
            }
        }
    }
    const int hd = blockIdx.x * 2 + wc;
    float as_[4], ad_[4];
#pragma unroll
    for (int j = 0; j < 4; ++j) {
        int c = j * 16 + l15;
        as_[j] = a_src[hd * CH + c];
        ad_[j] = a_dst[hd * CH + c];
    }
#pragma unroll
    for (int i = 0; i < 4; ++i) {
#pragma unroll
        for (int r = 0; r < 4; ++r) {
            float ps = 0.f, pd = 0.f;
#pragma unroll
            for (int j = 0; j < 4; ++j) {
                ps = fmaf(acc[i][j][r], as_[j], ps);
                pd = fmaf(acc[i][j][r], ad_[j], pd);
            }
#pragma unroll
            for (int mm = 8; mm; mm >>= 1) {
                ps += __shfl_xor(ps, mm);
                pd += __shfl_xor(pd, mm);
            }
            int row = m0 + wr * 64 + i * 16 + l4 * 4 + r;
            if (l15 == 0 && row < M) {
                es[row * NH + hd] = ps;
                ed[row * NH + hd] = pd;
            }
        }
    }
}

// ---- softmax -> head-major fp16 alpha planes: alphap[h][e] ----
// wave per node; lane layout (edge_slot, head) = (lane>>2, lane&3)
__global__ __launch_bounds__(256) void softmax_alpha_planes(const float* __restrict__ es,
                                                            const float* __restrict__ ed,
                                                            const int* __restrict__ rowptr,
                                                            const int* __restrict__ csr,
                                                            __half* __restrict__ alphap) {
    const int node = blockIdx.x * 4 + (threadIdx.x >> 6);
    const int lane = threadIdx.x & 63;
    if (node >= NN) return;
    const int start = rowptr[node];
    const int deg   = rowptr[node + 1] - start;

    const int hh = lane & 3;
    const int el = lane >> 2;
    float4 ed4 = *(const float4*)&ed[node * NH];
    float ednh = (hh & 1) ? ((hh & 2) ? ed4.w : ed4.y)
                          : ((hh & 2) ? ed4.z : ed4.x);

    float mx = -1e30f;
    for (int j = el; j < deg; j += 16) {
        int src = csr[start + j];
        float e = es[src * NH + hh] + ednh;
        e = (e > 0.f) ? e : NEG_SLOPE * e;
        mx = fmaxf(mx, e);
    }
#pragma unroll
    for (int off = 4; off < 64; off <<= 1) mx = fmaxf(mx, __shfl_xor(mx, off));

    float sm = 0.f;
    for (int j = el; j < deg; j += 16) {
        int src = csr[start + j];
        float e = es[src * NH + hh] + ednh;
        e = (e > 0.f) ? e : NEG_SLOPE * e;
        sm += __expf(e - mx);
    }
#pragma unroll
    for (int off = 4; off < 64; off <<= 1) sm += __shfl_xor(sm, off);
    const float inv = 1.0f / sm;

    for (int j = el; j < deg; j += 16) {
        int src = csr[start + j];
        float e = es[src * NH + hh] + ednh;
        e = (e > 0.f) ? e : NEG_SLOPE * e;
        alphap[(size_t)hh * ETOT + start + j] = __float2half(__expf(e - mx) * inv);
    }
}

// ---- channel-sliced gather: blockIdx = nodeGroup*8 + slice (slice -> XCD) ----
// slice c covers channels [c*32, c*32+32) == one aligned 64B column of hfeat.
// wave per node: 8 lane-groups x 8 lanes; group g takes edges g, g+8, ...;
// each lane loads 8B (4 channels). Butterfly over groups, lanes 0-7 store 64B.
__global__ __launch_bounds__(256) void gat_gather_sliced(const __half* __restrict__ hfeat,
                                                         const __half* __restrict__ alphap,
                                                         const int* __restrict__ rowptr,
                                                         const int* __restrict__ csr,
                                                         const float* __restrict__ bias,
                                                         __half* __restrict__ out16) {
    const int c    = blockIdx.x & 7;          // slice == XCD hint
    const int ng   = blockIdx.x >> 3;
    const int node = ng * 4 + (threadIdx.x >> 6);
    const int lane = threadIdx.x & 63;
    if (node >= NN) return;
    const int g      = lane >> 3;             // edge group 0..7
    const int cl     = lane & 7;              // channel sublane
    const int hs     = c >> 1;                // head of this slice
    const int chbase = c * 32 + cl * 4;
    const int start  = rowptr[node];
    const int deg    = rowptr[node + 1] - start;
    const __half* ap = alphap + (size_t)hs * ETOT;

    float a0 = 0.f, a1 = 0.f, a2 = 0.f, a3 = 0.f;
    for (int j = g; j < deg; j += 8) {
        int e   = start + j;
        int src = csr[e];
        float a = __half2float(ap[e]);
        uint2 r = *(const uint2*)&hfeat[(size_t)src * HC + chbase];
        float2 f0 = __half22float2(*reinterpret_cast<const __half2*>(&r.x));
        float2 f1 = __half22float2(*reinterpret_cast<const __half2*>(&r.y));
        a0 = fmaf(a, f0.x, a0);
        a1 = fmaf(a, f0.y, a1);
        a2 = fmaf(a, f1.x, a2);
        a3 = fmaf(a, f1.y, a3);
    }
#pragma unroll
    for (int off = 8; off < 64; off <<= 1) {
        a0 += __shfl_xor(a0, off);
        a1 += __shfl_xor(a1, off);
        a2 += __shfl_xor(a2, off);
        a3 += __shfl_xor(a3, off);
    }
    if (lane < 8) {
        float4 b = *(const float4*)&bias[chbase];
        __half h[4];
        h[0] = __float2half(fmaxf(a0 + b.x, 0.f));
        h[1] = __float2half(fmaxf(a1 + b.y, 0.f));
        h[2] = __float2half(fmaxf(a2 + b.z, 0.f));
        h[3] = __float2half(fmaxf(a3 + b.w, 0.f));
        *(uint2*)&out16[(size_t)node * HC + chbase] = *(uint2*)h;
    }
}

// ---------------- mean pool + final linear ----------------
__global__ __launch_bounds__(256) void pool_sum(const __half* __restrict__ h,
                                                const int* __restrict__ batch,
                                                float* __restrict__ sums) {
    int t  = threadIdx.x;
    int n0 = blockIdx.x * 128;
    if (n0 >= NN) return;
    int cur = batch[n0];
    float acc = 0.f;
    int nend = min(n0 + 128, NN);
    for (int n = n0; n < nend; ++n) {
        int g = batch[n];
        if (g != cur) {
            atomicAdd(&sums[cur * HC + t], acc);
            acc = 0.f; cur = g;
        }
        acc += __half2float(h[(size_t)n * HC + t]);
    }
    atomicAdd(&sums[cur * HC + t], acc);
}

__global__ void batch_bounds(const int* __restrict__ batch,
                             int* __restrict__ beg, int* __restrict__ end) {
    int i = blockIdx.x * 256 + threadIdx.x;
    if (i >= NN) return;
    int g = batch[i];
    if (i == 0      || batch[i - 1] != g) beg[g] = i;
    if (i == NN - 1 || batch[i + 1] != g) end[g] = i + 1;
}

__global__ __launch_bounds__(256) void final_linear(const float* __restrict__ sums,
                                                    const int* __restrict__ beg,
                                                    const int* __restrict__ end,
                                                    const float* __restrict__ Wlin,
                                                    const float* __restrict__ blin,
                                                    float* __restrict__ out) {
    int idx = blockIdx.x * 256 + threadIdx.x;
    if (idx >= NG * NOUT) return;
    int g = idx >> 4, o = idx & 15;
    float cnt = (float)(end[g] - beg[g]);
    float invc = 1.f / fmaxf(cnt, 1.f);
    float acc = 0.f;
    for (int k = 0; k < HC; ++k) acc += sums[g * HC + k] * Wlin[k * NOUT + o];
    out[idx] = acc * invc + blin[o];
}

// ---------------- launch ----------------
extern "C" void kernel_launch(void* const* d_in, const int* in_sizes, int n_in,
                              void* d_out, int out_size, void* d_ws, size_t ws_size,
                              hipStream_t stream) {
    const float* x      = (const float*)d_in[0];
    const int*   ei     = (const int*)d_in[1];
    const int*   batch  = (const int*)d_in[2];
    const float* W1     = (const float*)d_in[3];
    const float* a_src1 = (const float*)d_in[4];
    const float* a_dst1 = (const float*)d_in[5];
    const float* b1     = (const float*)d_in[6];
    const float* W2     = (const float*)d_in[7];
    const float* a_src2 = (const float*)d_in[8];
    const float* a_dst2 = (const float*)d_in[9];
    const float* b2     = (const float*)d_in[10];
    const float* Wlin   = (const float*)d_in[11];
    const float* blin   = (const float*)d_in[12];
    float* out = (float*)d_out;

    char* p = (char*)d_ws;
    auto take = [&](size_t bytes) {
        char* r = p;
        p += (bytes + 255) & ~(size_t)255;
        return r;
    };
    __half*   bufT16 = (__half*)take((size_t)NN * HC * 2);
    __half*   bufH16 = (__half*)take((size_t)NN * HC * 2);
    __half*   x16    = (__half*)take((size_t)NN * FIN * 2);
    __half*   w1t    = (__half*)take((size_t)FIN * HC * 2);
    __half*   w2t    = (__half*)take((size_t)HC * HC * 2);
    float*    es     = (float*)take((size_t)NN * NH * 4);
    float*    ed     = (float*)take((size_t)NN * NH * 4);
    int*      rowptr = (int*)take((size_t)(NN + 1) * 4);
    int*      csr    = (int*)take((size_t)ETOT * 4);
    unsigned* buckets= (unsigned*)take((size_t)NBUCK * BCAP * 4);
    int*      bcnt   = (int*)take((size_t)NBUCK * 4);
    int*      bbase  = (int*)take((size_t)NBUCK * 4);
    __half*   alphap = (__half*)take((size_t)NH * ETOT * 2);
    float*    sums   = (float*)take((size_t)NG * HC * 4);
    int*      gbeg   = (int*)take((size_t)NG * 4);
    int*      gend   = (int*)take((size_t)NG * 4);

    hipMemsetAsync(bcnt, 0, (size_t)NBUCK * 4, stream);
    hipMemsetAsync(sums, 0, (size_t)NG * HC * 4, stream);
    hipMemsetAsync(gbeg, 0, (size_t)NG * 4, stream);
    hipMemsetAsync(gend, 0, (size_t)NG * 4, stream);

    // CSR build (bucketed) + conversions
    edge_bucket<<<NEB, 256, 0, stream>>>(ei, bcnt, buckets);
    bucket_scan<<<1, 512, 0, stream>>>(bcnt, bbase, rowptr);
    bucket_to_csr<<<NBUCK, 256, 0, stream>>>(buckets, bcnt, bbase, rowptr, csr);
    f32_to_f16_vec<<<(NN * FIN / 4 + 255) / 256, 256, 0, stream>>>(x, x16, NN * FIN / 4);
    w_transpose_f16<<<(FIN * HC + 255) / 256, 256, 0, stream>>>(W1, w1t, FIN);
    w_transpose_f16<<<(HC * HC + 255) / 256, 256, 0, stream>>>(W2, w2t, HC);

    const int ngrp = (NN + 3) / 4;

    // layer 1
    gemm_f16<<<dim3(2, (NN + 127) / 128), 256, 0, stream>>>(x16, w1t, bufT16,
                                                            a_src1, a_dst1, es, ed, NN, FIN);
    softmax_alpha_planes<<<ngrp, 256, 0, stream>>>(es, ed, rowptr, csr, alphap);
    gat_gather_sliced<<<ngrp * 8, 256, 0, stream>>>(bufT16, alphap, rowptr, csr, b1, bufH16);

    // layer 2
    gemm_f16<<<dim3(2, (NN + 127) / 128), 256, 0, stream>>>(bufH16, w2t, bufT16,
                                                            a_src2, a_dst2, es, ed, NN, HC);
    softmax_alpha_planes<<<ngrp, 256, 0, stream>>>(es, ed, rowptr, csr, alphap);
    gat_gather_sliced<<<ngrp * 8, 256, 0, stream>>>(bufT16, alphap, rowptr, csr, b2, bufH16);

    // pool + head
    pool_sum<<<(NN + 127) / 128, 256, 0, stream>>>(bufH16, batch, sums);
    batch_bounds<<<(NN + 255) / 256, 256, 0, stream>>>(batch, gbeg, gend);
    final_linear<<<4, 256, 0, stream>>>(sums, gbeg, gend, Wlin, blin, out);
}

// Round 13
// 284.919 us; speedup vs baseline: 1.7965x; 1.7965x over previous
//
#include <hip/hip_runtime.h>
#include <hip/hip_fp16.h>

#define NN   50000
#define EE   800000
#define ETOT 850000   // EE + NN self loops
#define FIN  128
#define HC   256      // H*C
#define NH   4
#define CH   64
#define NG   64
#define NOUT 16
#define NEG_SLOPE 0.2f

#define NBUCK 391     // ceil(NN/128) dst-range buckets
#define BCAP  4096    // slots per bucket
#define EPB   4096    // edges per phase-1 block
#define NEB   208     // ceil(ETOT/EPB)

typedef _Float16 f16x8 __attribute__((ext_vector_type(8)));
typedef float    f32x4 __attribute__((ext_vector_type(4)));

// ======== CSR build: 2-phase dst-range bucketing ========
__global__ __launch_bounds__(256) void edge_bucket(const int* __restrict__ ei,
                                                   int* __restrict__ bucket_counts,
                                                   unsigned* __restrict__ buckets) {
    __shared__ int h[NBUCK];
    __shared__ int bb[NBUCK];
    const int tid = threadIdx.x;
    const int e0  = blockIdx.x * EPB;

    for (int t = tid; t < NBUCK; t += 256) h[t] = 0;
    __syncthreads();

    int srcs[16], dsts[16];
#pragma unroll
    for (int k = 0; k < 16; ++k) {
        int i = e0 + k * 256 + tid;
        int s = 0, d = -1;
        if (i < ETOT) {
            s = (i < EE) ? ei[i] : (i - EE);
            d = (i < EE) ? ei[EE + i] : (i - EE);
            atomicAdd(&h[d >> 7], 1);
        }
        srcs[k] = s; dsts[k] = d;
    }
    __syncthreads();

    for (int t = tid; t < NBUCK; t += 256) {
        bb[t] = atomicAdd(&bucket_counts[t], h[t]);
        h[t]  = 0;
    }
    __syncthreads();

#pragma unroll
    for (int k = 0; k < 16; ++k) {
        int d = dsts[k];
        if (d >= 0) {
            int b = d >> 7;
            int r = atomicAdd(&h[b], 1);
            int idx = bb[b] + r;
            if (idx < BCAP)
                buckets[(size_t)b * BCAP + idx] =
                    (unsigned)srcs[k] | ((unsigned)(d & 127) << 16);
        }
    }
}

__global__ __launch_bounds__(512) void bucket_scan(const int* __restrict__ counts,
                                                   int* __restrict__ basep,
                                                   int* __restrict__ rowptr) {
    __shared__ int lds[512];
    const int tid = threadIdx.x;
    int v = (tid < NBUCK) ? counts[tid] : 0;
    lds[tid] = v;
    __syncthreads();
    for (int off = 1; off < 512; off <<= 1) {
        int t = (tid >= off) ? lds[tid - off] : 0;
        __syncthreads();
        lds[tid] += t;
        __syncthreads();
    }
    if (tid < NBUCK) basep[tid] = lds[tid] - v;
    if (tid == 0) rowptr[NN] = ETOT;
}

__global__ __launch_bounds__(256) void bucket_to_csr(const unsigned* __restrict__ buckets,
                                                     const int* __restrict__ bucket_counts,
                                                     const int* __restrict__ bucket_base,
                                                     int* __restrict__ rowptr,
                                                     int* __restrict__ csr) {
    __shared__ int h[128], c[128], sc[128];
    const int b = blockIdx.x, tid = threadIdx.x;
    const int nb   = bucket_counts[b];
    const int base = bucket_base[b];

    if (tid < 128) h[tid] = 0;
    __syncthreads();
    for (int i = tid; i < nb; i += 256) {
        unsigned p = buckets[(size_t)b * BCAP + i];
        atomicAdd(&h[p >> 16], 1);
    }
    __syncthreads();
    if (tid < 128) sc[tid] = h[tid];
    __syncthreads();
    for (int off = 1; off < 128; off <<= 1) {
        int t = (tid < 128 && tid >= off) ? sc[tid - off] : 0;
        __syncthreads();
        if (tid < 128) sc[tid] += t;
        __syncthreads();
    }
    if (tid < 128) {
        int excl = sc[tid] - h[tid];
        c[tid] = excl;
        int node = (b << 7) + tid;
        if (node < NN) rowptr[node] = base + excl;
    }
    __syncthreads();
    for (int i = tid; i < nb; i += 256) {
        unsigned p = buckets[(size_t)b * BCAP + i];
        int pos = atomicAdd(&c[p >> 16], 1);
        csr[base + pos] = (int)(p & 0xFFFFu);
    }
}

// ---- fused conversions: x->fp16, W1->W1t fp16, W2->W2t fp16 ----
#define XB4 6250   // NN*FIN/4 / 256
#define W1B 128    // FIN*HC / 256
#define W2B 256    // HC*HC / 256
__global__ void prep_convert(const float* __restrict__ x, __half* __restrict__ x16,
                             const float* __restrict__ W1, __half* __restrict__ w1t,
                             const float* __restrict__ W2, __half* __restrict__ w2t) {
    int b = blockIdx.x;
    if (b < XB4) {
        int i = b * 256 + threadIdx.x;
        float4 v = *(const float4*)&x[(size_t)i * 4];
        __half h[4] = {__float2half(v.x), __float2half(v.y), __float2half(v.z), __float2half(v.w)};
        *(uint2*)&x16[(size_t)i * 4] = *(uint2*)h;
    } else if (b < XB4 + W1B) {
        int idx = (b - XB4) * 256 + threadIdx.x;   // [HC][FIN]
        int n = idx / FIN, k = idx - n * FIN;
        w1t[idx] = __float2half(W1[(size_t)k * HC + n]);
    } else {
        int idx = (b - XB4 - W1B) * 256 + threadIdx.x;  // [HC][HC]
        int n = idx / HC, k = idx - n * HC;
        w2t[idx] = __float2half(W2[(size_t)k * HC + n]);
    }
}

// ---- f16 MFMA GEMM + fused attention-score epilogue ----
// staging via global_load_lds width=16: LDS linear (dest = 16*tid), source
// column pre-swizzled by tcol ^ ((row&7)<<3) so swizzled ds_reads are unchanged.
__device__ __forceinline__ void load_lds_16B(const void* g, void* l) {
    __builtin_amdgcn_global_load_lds(
        (const __attribute__((address_space(1))) void*)g,
        (__attribute__((address_space(3))) void*)l, 16, 0, 0);
}

__global__ __launch_bounds__(256) void gemm_f16(const __half* __restrict__ A16,
                                                const __half* __restrict__ Bt16,
                                                __half* __restrict__ C16,
                                                const float* __restrict__ a_src,
                                                const float* __restrict__ a_dst,
                                                float* __restrict__ es,
                                                float* __restrict__ ed,
                                                int M, int K) {
    __shared__ char lds[32768];           // A 16KB | B 16KB, [128][64] fp16 swizzled
    const int tid  = threadIdx.x;
    const int m0   = blockIdx.y * 128;
    const int n0   = blockIdx.x * 128;
    const int wid  = tid >> 6, lane = tid & 63;
    const int wr   = wid >> 1, wc = wid & 1;
    const int l15  = lane & 15, l4 = lane >> 4;
    const int trow = tid >> 3;            // 0..31
    const int tcol = (tid & 7) * 8;       // fp16 units within 64-wide k slice
    const int scol = tcol ^ ((trow & 7) << 3);   // pre-swizzled source column

    f32x4 acc[4][4] = {};

    for (int k0 = 0; k0 < K; k0 += 64) {
        __syncthreads();
#pragma unroll
        for (int it = 0; it < 4; ++it) {
            int row = trow + it * 32;
            int gr  = m0 + row;
            int grc = (gr < M) ? gr : (M - 1);   // clamp; garbage rows never stored
            load_lds_16B(&A16[(size_t)grc * K + k0 + scol],
                         lds + it * 4096 + wid * 1024);
            load_lds_16B(&Bt16[(size_t)(n0 + row) * K + k0 + scol],
                         lds + 16384 + it * 4096 + wid * 1024);
        }
        __syncthreads();
#pragma unroll
        for (int ks = 0; ks < 2; ++ks) {
            f16x8 af[4], bf[4];
#pragma unroll
            for (int i = 0; i < 4; ++i) {
                int rowA = wr * 64 + i * 16 + l15;
                int offA = (rowA * 128 + ks * 64 + l4 * 16) ^ ((rowA & 7) << 4);
                af[i] = *(const f16x8*)(lds + offA);
                int rowB = wc * 64 + i * 16 + l15;
                int offB = 16384 + ((rowB * 128 + ks * 64 + l4 * 16) ^ ((rowB & 7) << 4));
                bf[i] = *(const f16x8*)(lds + offB);
            }
#pragma unroll
            for (int i = 0; i < 4; ++i)
#pragma unroll
                for (int j = 0; j < 4; ++j)
                    acc[i][j] = __builtin_amdgcn_mfma_f32_16x16x32_f16(af[i], bf[j], acc[i][j], 0, 0, 0);
        }
    }
#pragma unroll
    for (int i = 0; i < 4; ++i) {
#pragma unroll
        for (int r = 0; r < 4; ++r) {
            int row = m0 + wr * 64 + i * 16 + l4 * 4 + r;
            if (row < M) {
#pragma unroll
                for (int j = 0; j < 4; ++j) {
                    int col = n0 + wc * 64 + j * 16 + l15;
                    C16[(size_t)row * HC + col] = __float2half(acc[i][j][r]);
                }
            }
        }
    }
    const int hd = blockIdx.x * 2 + wc;
    float as_[4], ad_[4];
#pragma unroll
    for (int j = 0; j < 4; ++j) {
        int c = j * 16 + l15;
        as_[j] = a_src[hd * CH + c];
        ad_[j] = a_dst[hd * CH + c];
    }
#pragma unroll
    for (int i = 0; i < 4; ++i) {
#pragma unroll
        for (int r = 0; r < 4; ++r) {
            float ps = 0.f, pd = 0.f;
#pragma unroll
            for (int j = 0; j < 4; ++j) {
                ps = fmaf(acc[i][j][r], as_[j], ps);
                pd = fmaf(acc[i][j][r], ad_[j], pd);
            }
#pragma unroll
            for (int mm = 8; mm; mm >>= 1) {
                ps += __shfl_xor(ps, mm);
                pd += __shfl_xor(pd, mm);
            }
            int row = m0 + wr * 64 + i * 16 + l4 * 4 + r;
            if (l15 == 0 && row < M) {
                es[row * NH + hd] = ps;
                ed[row * NH + hd] = pd;
            }
        }
    }
}

// ------- fused softmax + gather: wave per node, two-pass exact softmax -------
__global__ __launch_bounds__(256) void gat_fused(const __half* __restrict__ hfeat,
                                                 const float* __restrict__ es,
                                                 const float* __restrict__ ed,
                                                 const int* __restrict__ rowptr,
                                                 const int* __restrict__ csr_src,
                                                 const float* __restrict__ bias,
                                                 __half* __restrict__ out16) {
    const int node = blockIdx.x * 4 + (threadIdx.x >> 6);
    const int lane = threadIdx.x & 63;
    if (node >= NN) return;
    const int start = rowptr[node];
    const int deg   = rowptr[node + 1] - start;

    const int hh = lane & 3;        // head for pass 1
    const int el = lane >> 2;       // edge slot 0..15
    float4 ed4 = *(const float4*)&ed[node * NH];
    float ednh = (hh & 1) ? ((hh & 2) ? ed4.w : ed4.y)
                          : ((hh & 2) ? ed4.z : ed4.x);

    // pass 1a: max (no transcendentals)
    float mx = -1e30f;
    for (int j = el; j < deg; j += 16) {
        int src = csr_src[start + j];
        float e = es[src * NH + hh] + ednh;
        e = (e > 0.f) ? e : NEG_SLOPE * e;
        mx = fmaxf(mx, e);
    }
#pragma unroll
    for (int off = 4; off < 64; off <<= 1) mx = fmaxf(mx, __shfl_xor(mx, off));

    // pass 1b: sum of exp
    float sm = 0.f;
    for (int j = el; j < deg; j += 16) {
        int src = csr_src[start + j];
        float e = es[src * NH + hh] + ednh;
        e = (e > 0.f) ? e : NEG_SLOPE * e;
        sm += __expf(e - mx);
    }
#pragma unroll
    for (int off = 4; off < 64; off <<= 1) sm += __shfl_xor(sm, off);

    // pass 2: paired-edge gather (16B/lane loads)
    const int sub = lane >> 5;
    const int cl  = lane & 31;
    const int hsel = cl >> 3;
    const float mh  = __shfl(mx, hsel);
    const float ish = 1.0f / __shfl(sm, hsel);
    const float ehn = __shfl(ednh, hsel);

    float acc[8] = {0.f, 0.f, 0.f, 0.f, 0.f, 0.f, 0.f, 0.f};
    int j = 0;
    for (; j + 3 < deg; j += 4) {
        int jj0 = start + j + sub;
        int jj1 = start + j + 2 + sub;
        int s0 = csr_src[jj0];
        int s1 = csr_src[jj1];
        float e0 = es[s0 * NH + hsel] + ehn;
        float e1 = es[s1 * NH + hsel] + ehn;
        e0 = (e0 > 0.f) ? e0 : NEG_SLOPE * e0;
        e1 = (e1 > 0.f) ? e1 : NEG_SLOPE * e1;
        float a0 = __expf(e0 - mh) * ish;
        float a1 = __expf(e1 - mh) * ish;
        uint4 r0 = *(const uint4*)&hfeat[(size_t)s0 * HC + cl * 8];
        uint4 r1 = *(const uint4*)&hfeat[(size_t)s1 * HC + cl * 8];
        const unsigned* w0 = &r0.x;
        const unsigned* w1 = &r1.x;
#pragma unroll
        for (int q = 0; q < 4; ++q) {
            float2 f0 = __half22float2(*reinterpret_cast<const __half2*>(&w0[q]));
            float2 f1 = __half22float2(*reinterpret_cast<const __half2*>(&w1[q]));
            acc[q * 2]     = fmaf(a0, f0.x, acc[q * 2]);
            acc[q * 2 + 1] = fmaf(a0, f0.y, acc[q * 2 + 1]);
            acc[q * 2]     = fmaf(a1, f1.x, acc[q * 2]);
            acc[q * 2 + 1] = fmaf(a1, f1.y, acc[q * 2 + 1]);
        }
    }
    for (; j < deg; j += 2) {
        int jj = j + sub;
        if (jj < deg) {
            int s0 = csr_src[start + jj];
            float e0 = es[s0 * NH + hsel] + ehn;
            e0 = (e0 > 0.f) ? e0 : NEG_SLOPE * e0;
            float a0 = __expf(e0 - mh) * ish;
            uint4 r0 = *(const uint4*)&hfeat[(size_t)s0 * HC + cl * 8];
            const unsigned* w0 = &r0.x;
#pragma unroll
            for (int q = 0; q < 4; ++q) {
                float2 f0 = __half22float2(*reinterpret_cast<const __half2*>(&w0[q]));
                acc[q * 2]     = fmaf(a0, f0.x, acc[q * 2]);
                acc[q * 2 + 1] = fmaf(a0, f0.y, acc[q * 2 + 1]);
            }
        }
    }
#pragma unroll
    for (int q = 0; q < 8; ++q) acc[q] += __shfl_xor(acc[q], 32);

    if (lane < 32) {
        float4 b0 = *(const float4*)&bias[cl * 8];
        float4 b1 = *(const float4*)&bias[cl * 8 + 4];
        const float* bp0 = &b0.x;
        const float* bp1 = &b1.x;
        __half h[8];
#pragma unroll
        for (int q = 0; q < 4; ++q) h[q]     = __float2half(fmaxf(acc[q]     + bp0[q], 0.f));
#pragma unroll
        for (int q = 0; q < 4; ++q) h[4 + q] = __float2half(fmaxf(acc[4 + q] + bp1[q], 0.f));
        *(uint4*)&out16[(size_t)node * HC + cl * 8] = *(uint4*)h;
    }
}

// ---------------- mean pool (half2) + final linear (binary search) ----------
__global__ __launch_bounds__(128) void pool_sum(const __half2* __restrict__ h2,
                                                const int* __restrict__ batch,
                                                float* __restrict__ sums) {
    int t  = threadIdx.x;            // channel pair 0..127
    int n0 = blockIdx.x * 128;
    if (n0 >= NN) return;
    int cur = batch[n0];
    float ax = 0.f, ay = 0.f;
    int nend = min(n0 + 128, NN);
    for (int n = n0; n < nend; ++n) {
        int g = batch[n];
        if (g != cur) {
            atomicAdd(&sums[cur * HC + 2 * t],     ax);
            atomicAdd(&sums[cur * HC + 2 * t + 1], ay);
            ax = ay = 0.f; cur = g;
        }
        float2 f = __half22float2(h2[(size_t)n * 128 + t]);
        ax += f.x; ay += f.y;
    }
    atomicAdd(&sums[cur * HC + 2 * t],     ax);
    atomicAdd(&sums[cur * HC + 2 * t + 1], ay);
}

__global__ __launch_bounds__(256) void final_linear(const float* __restrict__ sums,
                                                    const int* __restrict__ batch,
                                                    const float* __restrict__ Wlin,
                                                    const float* __restrict__ blin,
                                                    float* __restrict__ out) {
    int idx = blockIdx.x * 256 + threadIdx.x;
    if (idx >= NG * NOUT) return;
    int g = idx >> 4, o = idx & 15;
    // lower_bound / upper_bound on sorted batch
    int lo = 0, hi = NN;
    while (lo < hi) { int mid = (lo + hi) >> 1; if (batch[mid] < g) lo = mid + 1; else hi = mid; }
    int beg = lo;
    hi = NN;
    while (lo < hi) { int mid = (lo + hi) >> 1; if (batch[mid] <= g) lo = mid + 1; else hi = mid; }
    float cnt = (float)(lo - beg);
    float invc = 1.f / fmaxf(cnt, 1.f);
    float acc = 0.f;
    for (int k = 0; k < HC; ++k) acc += sums[g * HC + k] * Wlin[k * NOUT + o];
    out[idx] = acc * invc + blin[o];
}

// ---------------- launch ----------------
extern "C" void kernel_launch(void* const* d_in, const int* in_sizes, int n_in,
                              void* d_out, int out_size, void* d_ws, size_t ws_size,
                              hipStream_t stream) {
    const float* x      = (const float*)d_in[0];
    const int*   ei     = (const int*)d_in[1];
    const int*   batch  = (const int*)d_in[2];
    const float* W1     = (const float*)d_in[3];
    const float* a_src1 = (const float*)d_in[4];
    const float* a_dst1 = (const float*)d_in[5];
    const float* b1     = (const float*)d_in[6];
    const float* W2     = (const float*)d_in[7];
    const float* a_src2 = (const float*)d_in[8];
    const float* a_dst2 = (const float*)d_in[9];
    const float* b2     = (const float*)d_in[10];
    const float* Wlin   = (const float*)d_in[11];
    const float* blin   = (const float*)d_in[12];
    float* out = (float*)d_out;

    char* p = (char*)d_ws;
    auto take = [&](size_t bytes) {
        char* r = p;
        p += (bytes + 255) & ~(size_t)255;
        return r;
    };
    __half*   bufT16 = (__half*)take((size_t)NN * HC * 2);
    __half*   bufH16 = (__half*)take((size_t)NN * HC * 2);
    __half*   x16    = (__half*)take((size_t)NN * FIN * 2);
    __half*   w1t    = (__half*)take((size_t)FIN * HC * 2);
    __half*   w2t    = (__half*)take((size_t)HC * HC * 2);
    float*    es     = (float*)take((size_t)NN * NH * 4);
    float*    ed     = (float*)take((size_t)NN * NH * 4);
    int*      rowptr = (int*)take((size_t)(NN + 1) * 4);
    int*      csr    = (int*)take((size_t)ETOT * 4);
    unsigned* buckets= (unsigned*)take((size_t)NBUCK * BCAP * 4);
    int*      bbase  = (int*)take((size_t)NBUCK * 4);
    // zero-region: sums | bcnt — one memset
    char*     zbase  = take((size_t)NG * HC * 4 + (size_t)NBUCK * 4);
    float*    sums   = (float*)zbase;
    int*      bcnt   = (int*)(zbase + (size_t)NG * HC * 4);

    hipMemsetAsync(zbase, 0, (size_t)NG * HC * 4 + (size_t)NBUCK * 4, stream);

    // CSR build + conversions
    edge_bucket<<<NEB, 256, 0, stream>>>(ei, bcnt, buckets);
    bucket_scan<<<1, 512, 0, stream>>>(bcnt, bbase, rowptr);
    bucket_to_csr<<<NBUCK, 256, 0, stream>>>(buckets, bcnt, bbase, rowptr, csr);
    prep_convert<<<XB4 + W1B + W2B, 256, 0, stream>>>(x, x16, W1, w1t, W2, w2t);

    // layer 1
    gemm_f16<<<dim3(2, (NN + 127) / 128), 256, 0, stream>>>(x16, w1t, bufT16,
                                                            a_src1, a_dst1, es, ed, NN, FIN);
    gat_fused<<<(NN + 3) / 4, 256, 0, stream>>>(bufT16, es, ed, rowptr, csr, b1, bufH16);

    // layer 2
    gemm_f16<<<dim3(2, (NN + 127) / 128), 256, 0, stream>>>(bufH16, w2t, bufT16,
                                                            a_src2, a_dst2, es, ed, NN, HC);
    gat_fused<<<(NN + 3) / 4, 256, 0, stream>>>(bufT16, es, ed, rowptr, csr, b2, bufH16);

    // pool + head
    pool_sum<<<(NN + 127) / 128, 128, 0, stream>>>((const __half2*)bufH16, batch, sums);
    final_linear<<<4, 256, 0, stream>>>(sums, batch, Wlin, blin, out);
}

// Round 14
// 282.885 us; speedup vs baseline: 1.8095x; 1.0072x over previous
//
#include <hip/hip_runtime.h>
#include <hip/hip_fp16.h>

#define NN   50000
#define EE   800000
#define ETOT 850000   // EE + NN self loops
#define FIN  128
#define HC   256      // H*C
#define NH   4
#define CH   64
#define NG   64
#define NOUT 16
#define NEG_SLOPE 0.2f

#define NBUCK 391     // ceil(NN/128) dst-range buckets
#define BCAP  4096    // slots per bucket
#define EPB   4096    // edges per phase-1 block
#define NEB   208     // ceil(ETOT/EPB)

typedef _Float16 f16x8 __attribute__((ext_vector_type(8)));
typedef float    f32x4 __attribute__((ext_vector_type(4)));

// ======== CSR build: 2-phase dst-range bucketing ========
__global__ __launch_bounds__(256) void edge_bucket(const int* __restrict__ ei,
                                                   int* __restrict__ bucket_counts,
                                                   unsigned* __restrict__ buckets) {
    __shared__ int h[NBUCK];
    __shared__ int bb[NBUCK];
    const int tid = threadIdx.x;
    const int e0  = blockIdx.x * EPB;

    for (int t = tid; t < NBUCK; t += 256) h[t] = 0;
    __syncthreads();

    int srcs[16], dsts[16];
#pragma unroll
    for (int k = 0; k < 16; ++k) {
        int i = e0 + k * 256 + tid;
        int s = 0, d = -1;
        if (i < ETOT) {
            s = (i < EE) ? ei[i] : (i - EE);
            d = (i < EE) ? ei[EE + i] : (i - EE);
            atomicAdd(&h[d >> 7], 1);
        }
        srcs[k] = s; dsts[k] = d;
    }
    __syncthreads();

    for (int t = tid; t < NBUCK; t += 256) {
        bb[t] = atomicAdd(&bucket_counts[t], h[t]);
        h[t]  = 0;
    }
    __syncthreads();

#pragma unroll
    for (int k = 0; k < 16; ++k) {
        int d = dsts[k];
        if (d >= 0) {
            int b = d >> 7;
            int r = atomicAdd(&h[b], 1);
            int idx = bb[b] + r;
            if (idx < BCAP)
                buckets[(size_t)b * BCAP + idx] =
                    (unsigned)srcs[k] | ((unsigned)(d & 127) << 16);
        }
    }
}

__global__ __launch_bounds__(512) void bucket_scan(const int* __restrict__ counts,
                                                   int* __restrict__ basep,
                                                   int* __restrict__ rowptr) {
    __shared__ int lds[512];
    const int tid = threadIdx.x;
    int v = (tid < NBUCK) ? counts[tid] : 0;
    lds[tid] = v;
    __syncthreads();
    for (int off = 1; off < 512; off <<= 1) {
        int t = (tid >= off) ? lds[tid - off] : 0;
        __syncthreads();
        lds[tid] += t;
        __syncthreads();
    }
    if (tid < NBUCK) basep[tid] = lds[tid] - v;
    if (tid == 0) rowptr[NN] = ETOT;
}

__global__ __launch_bounds__(256) void bucket_to_csr(const unsigned* __restrict__ buckets,
                                                     const int* __restrict__ bucket_counts,
                                                     const int* __restrict__ bucket_base,
                                                     int* __restrict__ rowptr,
                                                     int* __restrict__ csr) {
    __shared__ int h[128], c[128], sc[128];
    const int b = blockIdx.x, tid = threadIdx.x;
    const int nb   = bucket_counts[b];
    const int base = bucket_base[b];

    if (tid < 128) h[tid] = 0;
    __syncthreads();
    for (int i = tid; i < nb; i += 256) {
        unsigned p = buckets[(size_t)b * BCAP + i];
        atomicAdd(&h[p >> 16], 1);
    }
    __syncthreads();
    if (tid < 128) sc[tid] = h[tid];
    __syncthreads();
    for (int off = 1; off < 128; off <<= 1) {
        int t = (tid < 128 && tid >= off) ? sc[tid - off] : 0;
        __syncthreads();
        if (tid < 128) sc[tid] += t;
        __syncthreads();
    }
    if (tid < 128) {
        int excl = sc[tid] - h[tid];
        c[tid] = excl;
        int node = (b << 7) + tid;
        if (node < NN) rowptr[node] = base + excl;
    }
    __syncthreads();
    for (int i = tid; i < nb; i += 256) {
        unsigned p = buckets[(size_t)b * BCAP + i];
        int pos = atomicAdd(&c[p >> 16], 1);
        csr[base + pos] = (int)(p & 0xFFFFu);
    }
}

// ---- fused conversions: x->fp16, W1->W1t fp16, W2->W2t fp16 ----
#define XB4 6250   // NN*FIN/4 / 256
#define W1B 128    // FIN*HC / 256
#define W2B 256    // HC*HC / 256
__global__ void prep_convert(const float* __restrict__ x, __half* __restrict__ x16,
                             const float* __restrict__ W1, __half* __restrict__ w1t,
                             const float* __restrict__ W2, __half* __restrict__ w2t) {
    int b = blockIdx.x;
    if (b < XB4) {
        int i = b * 256 + threadIdx.x;
        float4 v = *(const float4*)&x[(size_t)i * 4];
        __half h[4] = {__float2half(v.x), __float2half(v.y), __float2half(v.z), __float2half(v.w)};
        *(uint2*)&x16[(size_t)i * 4] = *(uint2*)h;
    } else if (b < XB4 + W1B) {
        int idx = (b - XB4) * 256 + threadIdx.x;   // [HC][FIN]
        int n = idx / FIN, k = idx - n * FIN;
        w1t[idx] = __float2half(W1[(size_t)k * HC + n]);
    } else {
        int idx = (b - XB4 - W1B) * 256 + threadIdx.x;  // [HC][HC]
        int n = idx / HC, k = idx - n * HC;
        w2t[idx] = __float2half(W2[(size_t)k * HC + n]);
    }
}

// ---- f16 MFMA GEMM + fused attention-score epilogue ----
__device__ __forceinline__ void load_lds_16B(const void* g, void* l) {
    __builtin_amdgcn_global_load_lds(
        (const __attribute__((address_space(1))) void*)g,
        (__attribute__((address_space(3))) void*)l, 16, 0, 0);
}

__global__ __launch_bounds__(256) void gemm_f16(const __half* __restrict__ A16,
                                                const __half* __restrict__ Bt16,
                                                __half* __restrict__ C16,
                                                const float* __restrict__ a_src,
                                                const float* __restrict__ a_dst,
                                                float* __restrict__ es,
                                                float* __restrict__ ed,
                                                int M, int K) {
    __shared__ char lds[32768];           // A 16KB | B 16KB, [128][64] fp16 swizzled
    const int tid  = threadIdx.x;
    const int m0   = blockIdx.y * 128;
    const int n0   = blockIdx.x * 128;
    const int wid  = tid >> 6, lane = tid & 63;
    const int wr   = wid >> 1, wc = wid & 1;
    const int l15  = lane & 15, l4 = lane >> 4;
    const int trow = tid >> 3;            // 0..31
    const int tcol = (tid & 7) * 8;       // fp16 units within 64-wide k slice
    const int scol = tcol ^ ((trow & 7) << 3);   // pre-swizzled source column

    f32x4 acc[4][4] = {};

    for (int k0 = 0; k0 < K; k0 += 64) {
        __syncthreads();
#pragma unroll
        for (int it = 0; it < 4; ++it) {
            int row = trow + it * 32;
            int gr  = m0 + row;
            int grc = (gr < M) ? gr : (M - 1);   // clamp; garbage rows never stored
            load_lds_16B(&A16[(size_t)grc * K + k0 + scol],
                         lds + it * 4096 + wid * 1024);
            load_lds_16B(&Bt16[(size_t)(n0 + row) * K + k0 + scol],
                         lds + 16384 + it * 4096 + wid * 1024);
        }
        __syncthreads();
#pragma unroll
        for (int ks = 0; ks < 2; ++ks) {
            f16x8 af[4], bf[4];
#pragma unroll
            for (int i = 0; i < 4; ++i) {
                int rowA = wr * 64 + i * 16 + l15;
                int offA = (rowA * 128 + ks * 64 + l4 * 16) ^ ((rowA & 7) << 4);
                af[i] = *(const f16x8*)(lds + offA);
                int rowB = wc * 64 + i * 16 + l15;
                int offB = 16384 + ((rowB * 128 + ks * 64 + l4 * 16) ^ ((rowB & 7) << 4));
                bf[i] = *(const f16x8*)(lds + offB);
            }
#pragma unroll
            for (int i = 0; i < 4; ++i)
#pragma unroll
                for (int j = 0; j < 4; ++j)
                    acc[i][j] = __builtin_amdgcn_mfma_f32_16x16x32_f16(af[i], bf[j], acc[i][j], 0, 0, 0);
        }
    }
#pragma unroll
    for (int i = 0; i < 4; ++i) {
#pragma unroll
        for (int r = 0; r < 4; ++r) {
            int row = m0 + wr * 64 + i * 16 + l4 * 4 + r;
            if (row < M) {
#pragma unroll
                for (int j = 0; j < 4; ++j) {
                    int col = n0 + wc * 64 + j * 16 + l15;
                    C16[(size_t)row * HC + col] = __float2half(acc[i][j][r]);
                }
            }
        }
    }
    const int hd = blockIdx.x * 2 + wc;
    float as_[4], ad_[4];
#pragma unroll
    for (int j = 0; j < 4; ++j) {
        int c = j * 16 + l15;
        as_[j] = a_src[hd * CH + c];
        ad_[j] = a_dst[hd * CH + c];
    }
#pragma unroll
    for (int i = 0; i < 4; ++i) {
#pragma unroll
        for (int r = 0; r < 4; ++r) {
            float ps = 0.f, pd = 0.f;
#pragma unroll
            for (int j = 0; j < 4; ++j) {
                ps = fmaf(acc[i][j][r], as_[j], ps);
                pd = fmaf(acc[i][j][r], ad_[j], pd);
            }
#pragma unroll
            for (int mm = 8; mm; mm >>= 1) {
                ps += __shfl_xor(ps, mm);
                pd += __shfl_xor(pd, mm);
            }
            int row = m0 + wr * 64 + i * 16 + l4 * 4 + r;
            if (l15 == 0 && row < M) {
                es[row * NH + hd] = ps;
                ed[row * NH + hd] = pd;
            }
        }
    }
}

// ------- fused softmax + gather: wave per node, two-pass exact softmax -------
// pass 2 unrolled to 8 edges/iter (4 per half-wave): 4 uint4 feature loads in
// flight per lane to attack gather latency (occupancy 69%, VGPR headroom).
__global__ __launch_bounds__(256) void gat_fused(const __half* __restrict__ hfeat,
                                                 const float* __restrict__ es,
                                                 const float* __restrict__ ed,
                                                 const int* __restrict__ rowptr,
                                                 const int* __restrict__ csr_src,
                                                 const float* __restrict__ bias,
                                                 __half* __restrict__ out16) {
    const int node = blockIdx.x * 4 + (threadIdx.x >> 6);
    const int lane = threadIdx.x & 63;
    if (node >= NN) return;
    const int start = rowptr[node];
    const int deg   = rowptr[node + 1] - start;

    const int hh = lane & 3;        // head for pass 1
    const int el = lane >> 2;       // edge slot 0..15
    float4 ed4 = *(const float4*)&ed[node * NH];
    float ednh = (hh & 1) ? ((hh & 2) ? ed4.w : ed4.y)
                          : ((hh & 2) ? ed4.z : ed4.x);

    // pass 1a: max (no transcendentals)
    float mx = -1e30f;
    for (int j = el; j < deg; j += 16) {
        int src = csr_src[start + j];
        float e = es[src * NH + hh] + ednh;
        e = (e > 0.f) ? e : NEG_SLOPE * e;
        mx = fmaxf(mx, e);
    }
#pragma unroll
    for (int off = 4; off < 64; off <<= 1) mx = fmaxf(mx, __shfl_xor(mx, off));

    // pass 1b: sum of exp
    float sm = 0.f;
    for (int j = el; j < deg; j += 16) {
        int src = csr_src[start + j];
        float e = es[src * NH + hh] + ednh;
        e = (e > 0.f) ? e : NEG_SLOPE * e;
        sm += __expf(e - mx);
    }
#pragma unroll
    for (int off = 4; off < 64; off <<= 1) sm += __shfl_xor(sm, off);

    // pass 2: 8-edge unrolled gather, 16B/lane loads, 4-deep MLP
    const int sub = lane >> 5;
    const int cl  = lane & 31;
    const int hsel = cl >> 3;
    const float mh  = __shfl(mx, hsel);
    const float ish = 1.0f / __shfl(sm, hsel);
    const float ehn = __shfl(ednh, hsel);

    float acc[8] = {0.f, 0.f, 0.f, 0.f, 0.f, 0.f, 0.f, 0.f};
    int j = 0;
    for (; j + 7 < deg; j += 8) {
        const int e = start + j + sub;
        int i0 = csr_src[e + 0];
        int i1 = csr_src[e + 2];
        int i2 = csr_src[e + 4];
        int i3 = csr_src[e + 6];
        float e0 = es[i0 * NH + hsel] + ehn;
        float e1 = es[i1 * NH + hsel] + ehn;
        float e2 = es[i2 * NH + hsel] + ehn;
        float e3 = es[i3 * NH + hsel] + ehn;
        uint4 r0 = *(const uint4*)&hfeat[(size_t)i0 * HC + cl * 8];
        uint4 r1 = *(const uint4*)&hfeat[(size_t)i1 * HC + cl * 8];
        uint4 r2 = *(const uint4*)&hfeat[(size_t)i2 * HC + cl * 8];
        uint4 r3 = *(const uint4*)&hfeat[(size_t)i3 * HC + cl * 8];
        e0 = (e0 > 0.f) ? e0 : NEG_SLOPE * e0;
        e1 = (e1 > 0.f) ? e1 : NEG_SLOPE * e1;
        e2 = (e2 > 0.f) ? e2 : NEG_SLOPE * e2;
        e3 = (e3 > 0.f) ? e3 : NEG_SLOPE * e3;
        float a0 = __expf(e0 - mh) * ish;
        float a1 = __expf(e1 - mh) * ish;
        float a2 = __expf(e2 - mh) * ish;
        float a3 = __expf(e3 - mh) * ish;
        const unsigned* w0 = &r0.x;
        const unsigned* w1 = &r1.x;
        const unsigned* w2 = &r2.x;
        const unsigned* w3 = &r3.x;
#pragma unroll
        for (int q = 0; q < 4; ++q) {
            float2 f0 = __half22float2(*reinterpret_cast<const __half2*>(&w0[q]));
            float2 f1 = __half22float2(*reinterpret_cast<const __half2*>(&w1[q]));
            float2 f2 = __half22float2(*reinterpret_cast<const __half2*>(&w2[q]));
            float2 f3 = __half22float2(*reinterpret_cast<const __half2*>(&w3[q]));
            acc[q * 2]     = fmaf(a0, f0.x, acc[q * 2]);
            acc[q * 2 + 1] = fmaf(a0, f0.y, acc[q * 2 + 1]);
            acc[q * 2]     = fmaf(a1, f1.x, acc[q * 2]);
            acc[q * 2 + 1] = fmaf(a1, f1.y, acc[q * 2 + 1]);
            acc[q * 2]     = fmaf(a2, f2.x, acc[q * 2]);
            acc[q * 2 + 1] = fmaf(a2, f2.y, acc[q * 2 + 1]);
            acc[q * 2]     = fmaf(a3, f3.x, acc[q * 2]);
            acc[q * 2 + 1] = fmaf(a3, f3.y, acc[q * 2 + 1]);
        }
    }
    for (; j < deg; j += 2) {
        int jj = j + sub;
        if (jj < deg) {
            int s0 = csr_src[start + jj];
            float e0 = es[s0 * NH + hsel] + ehn;
            e0 = (e0 > 0.f) ? e0 : NEG_SLOPE * e0;
            float a0 = __expf(e0 - mh) * ish;
            uint4 r0 = *(const uint4*)&hfeat[(size_t)s0 * HC + cl * 8];
            const unsigned* w0 = &r0.x;
#pragma unroll
            for (int q = 0; q < 4; ++q) {
                float2 f0 = __half22float2(*reinterpret_cast<const __half2*>(&w0[q]));
                acc[q * 2]     = fmaf(a0, f0.x, acc[q * 2]);
                acc[q * 2 + 1] = fmaf(a0, f0.y, acc[q * 2 + 1]);
            }
        }
    }
#pragma unroll
    for (int q = 0; q < 8; ++q) acc[q] += __shfl_xor(acc[q], 32);

    if (lane < 32) {
        float4 b0 = *(const float4*)&bias[cl * 8];
        float4 b1 = *(const float4*)&bias[cl * 8 + 4];
        const float* bp0 = &b0.x;
        const float* bp1 = &b1.x;
        __half h[8];
#pragma unroll
        for (int q = 0; q < 4; ++q) h[q]     = __float2half(fmaxf(acc[q]     + bp0[q], 0.f));
#pragma unroll
        for (int q = 0; q < 4; ++q) h[4 + q] = __float2half(fmaxf(acc[4 + q] + bp1[q], 0.f));
        *(uint4*)&out16[(size_t)node * HC + cl * 8] = *(uint4*)h;
    }
}

// ---------------- mean pool (half2) + final linear (binary search) ----------
__global__ __launch_bounds__(128) void pool_sum(const __half2* __restrict__ h2,
                                                const int* __restrict__ batch,
                                                float* __restrict__ sums) {
    int t  = threadIdx.x;            // channel pair 0..127
    int n0 = blockIdx.x * 128;
    if (n0 >= NN) return;
    int cur = batch[n0];
    float ax = 0.f, ay = 0.f;
    int nend = min(n0 + 128, NN);
    for (int n = n0; n < nend; ++n) {
        int g = batch[n];
        if (g != cur) {
            atomicAdd(&sums[cur * HC + 2 * t],     ax);
            atomicAdd(&sums[cur * HC + 2 * t + 1], ay);
            ax = ay = 0.f; cur = g;
        }
        float2 f = __half22float2(h2[(size_t)n * 128 + t]);
        ax += f.x; ay += f.y;
    }
    atomicAdd(&sums[cur * HC + 2 * t],     ax);
    atomicAdd(&sums[cur * HC + 2 * t + 1], ay);
}

__global__ __launch_bounds__(256) void final_linear(const float* __restrict__ sums,
                                                    const int* __restrict__ batch,
                                                    const float* __restrict__ Wlin,
                                                    const float* __restrict__ blin,
                                                    float* __restrict__ out) {
    int idx = blockIdx.x * 256 + threadIdx.x;
    if (idx >= NG * NOUT) return;
    int g = idx >> 4, o = idx & 15;
    int lo = 0, hi = NN;
    while (lo < hi) { int mid = (lo + hi) >> 1; if (batch[mid] < g) lo = mid + 1; else hi = mid; }
    int beg = lo;
    hi = NN;
    while (lo < hi) { int mid = (lo + hi) >> 1; if (batch[mid] <= g) lo = mid + 1; else hi = mid; }
    float cnt = (float)(lo - beg);
    float invc = 1.f / fmaxf(cnt, 1.f);
    float acc = 0.f;
    for (int k = 0; k < HC; ++k) acc += sums[g * HC + k] * Wlin[k * NOUT + o];
    out[idx] = acc * invc + blin[o];
}

// ---------------- launch ----------------
extern "C" void kernel_launch(void* const* d_in, const int* in_sizes, int n_in,
                              void* d_out, int out_size, void* d_ws, size_t ws_size,
                              hipStream_t stream) {
    const float* x      = (const float*)d_in[0];
    const int*   ei     = (const int*)d_in[1];
    const int*   batch  = (const int*)d_in[2];
    const float* W1     = (const float*)d_in[3];
    const float* a_src1 = (const float*)d_in[4];
    const float* a_dst1 = (const float*)d_in[5];
    const float* b1     = (const float*)d_in[6];
    const float* W2     = (const float*)d_in[7];
    const float* a_src2 = (const float*)d_in[8];
    const float* a_dst2 = (const float*)d_in[9];
    const float* b2     = (const float*)d_in[10];
    const float* Wlin   = (const float*)d_in[11];
    const float* blin   = (const float*)d_in[12];
    float* out = (float*)d_out;

    char* p = (char*)d_ws;
    auto take = [&](size_t bytes) {
        char* r = p;
        p += (bytes + 255) & ~(size_t)255;
        return r;
    };
    __half*   bufT16 = (__half*)take((size_t)NN * HC * 2);
    __half*   bufH16 = (__half*)take((size_t)NN * HC * 2);
    __half*   x16    = (__half*)take((size_t)NN * FIN * 2);
    __half*   w1t    = (__half*)take((size_t)FIN * HC * 2);
    __half*   w2t    = (__half*)take((size_t)HC * HC * 2);
    float*    es     = (float*)take((size_t)NN * NH * 4);
    float*    ed     = (float*)take((size_t)NN * NH * 4);
    int*      rowptr = (int*)take((size_t)(NN + 1) * 4);
    int*      csr    = (int*)take((size_t)ETOT * 4);
    unsigned* buckets= (unsigned*)take((size_t)NBUCK * BCAP * 4);
    int*      bbase  = (int*)take((size_t)NBUCK * 4);
    char*     zbase  = take((size_t)NG * HC * 4 + (size_t)NBUCK * 4);
    float*    sums   = (float*)zbase;
    int*      bcnt   = (int*)(zbase + (size_t)NG * HC * 4);

    hipMemsetAsync(zbase, 0, (size_t)NG * HC * 4 + (size_t)NBUCK * 4, stream);

    // CSR build + conversions
    edge_bucket<<<NEB, 256, 0, stream>>>(ei, bcnt, buckets);
    bucket_scan<<<1, 512, 0, stream>>>(bcnt, bbase, rowptr);
    bucket_to_csr<<<NBUCK, 256, 0, stream>>>(buckets, bcnt, bbase, rowptr, csr);
    prep_convert<<<XB4 + W1B + W2B, 256, 0, stream>>>(x, x16, W1, w1t, W2, w2t);

    // layer 1
    gemm_f16<<<dim3(2, (NN + 127) / 128), 256, 0, stream>>>(x16, w1t, bufT16,
                                                            a_src1, a_dst1, es, ed, NN, FIN);
    gat_fused<<<(NN + 3) / 4, 256, 0, stream>>>(bufT16, es, ed, rowptr, csr, b1, bufH16);

    // layer 2
    gemm_f16<<<dim3(2, (NN + 127) / 128), 256, 0, stream>>>(bufH16, w2t, bufT16,
                                                            a_src2, a_dst2, es, ed, NN, HC);
    gat_fused<<<(NN + 3) / 4, 256, 0, stream>>>(bufT16, es, ed, rowptr, csr, b2, bufH16);

    // pool + head
    pool_sum<<<(NN + 127) / 128, 128, 0, stream>>>((const __half2*)bufH16, batch, sums);
    final_linear<<<4, 256, 0, stream>>>(sums, batch, Wlin, blin, out);
}